// Round 15
// baseline (259.093 us; speedup 1.0000x reference)
//
#include <hip/hip_runtime.h>
#include <hip/hip_bf16.h>

#define NPIX 6400
#define LOG2E 1.44269504088896340736f
#define KH 10         // split-K ways -> grid 2000
#define KEYS 640      // keys per split
#define NSTEP 40      // 16-key steps per block = KEYS/16
#define QF 2          // query fragments (16q each) per wave

typedef _Float16 half_t;
typedef _Float16 half4 __attribute__((ext_vector_type(4)));
typedef __fp16 fp16x2 __attribute__((ext_vector_type(2)));
typedef float float4x __attribute__((ext_vector_type(4)));

__device__ __forceinline__ float fast_exp2(float x) {
    float r;
    asm volatile("v_exp_f32 %0, %1" : "=v"(r) : "v"(x));
    return r;
}

__device__ __forceinline__ half4 cvtf4(float4x v) {
    union { fp16x2 h2[2]; half4 h4; } u;
    u.h2[0] = __builtin_amdgcn_cvt_pkrtz(v[0], v[1]);
    u.h2[1] = __builtin_amdgcn_cvt_pkrtz(v[2], v[3]);
    return u.h4;
}

// ---------------- MFMA projections + workspace zeroing ----------------
// blocks 0..199: 4 independent waves each own (bz, 16-pixel group); per wave:
//   7 weight-tiles (qab | kab+kbc | qbc | wv x4) x 4 k-tiles of 16x16x16 MFMA.
//   A-frag = weights (row-major [out][64], float4 -> fp16, predicated rows),
//   B-frag = input pixels (4 strided floats -> fp16). D: col=pix=lane&15, row=4g+r.
// blocks 200..263: zero num+lsum (416000 float4)
__global__ __launch_bounds__(256) void proj_kernel(
    const float* __restrict__ a, const float* __restrict__ b, const float* __restrict__ c,
    const float* __restrict__ wq_ab, const float* __restrict__ bq_ab,
    const float* __restrict__ wk_ab, const float* __restrict__ bk_ab,
    const float* __restrict__ wq_bc, const float* __restrict__ bq_bc,
    const float* __restrict__ wk_bc, const float* __restrict__ bk_bc,
    const float* __restrict__ wv, const float* __restrict__ bvb,
    half_t* __restrict__ qp, half_t* __restrict__ kp, half_t* __restrict__ vp,
    float* __restrict__ num)
{
    int bid = blockIdx.x;
    int tid = threadIdx.x;
    if (bid >= 200) {
        int t = (bid - 200) * 256 + tid;     // 0..16383
        float4x z = {0.f, 0.f, 0.f, 0.f};
        float4x* p = (float4x*)num;
        for (int i = t; i < 416000; i += 16384) p[i] = z;
        return;
    }
    int wid = bid * 4 + (tid >> 6);          // 0..799
    int lane = tid & 63;
    int m = lane & 15, g = lane >> 4;
    int bz = wid / 400;
    int pix0 = (wid % 400) * 16;
    const float* Ain = a + bz * 64 * NPIX + pix0 + m;
    const float* Bin = b + bz * 64 * NPIX + pix0 + m;
    const float* Cin = c + bz * 64 * NPIX + pix0 + m;

    float4x zf = {0.f, 0.f, 0.f, 0.f};
    float4x acc_qa = zf, acc_k = zf, acc_qc = zf;
    float4x acc_v0 = zf, acc_v1 = zf, acc_v2 = zf, acc_v3 = zf;
    half4 hz = {(half_t)0, (half_t)0, (half_t)0, (half_t)0};

#pragma unroll
    for (int kt = 0; kt < 4; ++kt) {
        int ch0 = kt * 16 + g * 4;
        float4x fa, fb, fc;
#pragma unroll
        for (int j = 0; j < 4; ++j) {
            fa[j] = Ain[(ch0 + j) * NPIX];
            fb[j] = Bin[(ch0 + j) * NPIX];
            fc[j] = Cin[(ch0 + j) * NPIX];
        }
        half4 ba = cvtf4(fa), bb = cvtf4(fb), bc_ = cvtf4(fc);
        half4 wa = hz, w0 = hz, wc = hz;
        if (m < 4) {
            wa = cvtf4(*(const float4x*)(wq_ab + m * 64 + ch0));
            w0 = cvtf4(*(const float4x*)(wk_ab + m * 64 + ch0));
            wc = cvtf4(*(const float4x*)(wq_bc + m * 64 + ch0));
        } else if (m < 8) {
            w0 = cvtf4(*(const float4x*)(wk_bc + (m - 4) * 64 + ch0));
        }
        acc_qa = __builtin_amdgcn_mfma_f32_16x16x16f16(wa, ba, acc_qa, 0, 0, 0);
        acc_k  = __builtin_amdgcn_mfma_f32_16x16x16f16(w0, bb, acc_k, 0, 0, 0);
        acc_qc = __builtin_amdgcn_mfma_f32_16x16x16f16(wc, bc_, acc_qc, 0, 0, 0);
        half4 wv0 = cvtf4(*(const float4x*)(wv + (0 * 16 + m) * 64 + ch0));
        acc_v0 = __builtin_amdgcn_mfma_f32_16x16x16f16(wv0, bb, acc_v0, 0, 0, 0);
        half4 wv1 = cvtf4(*(const float4x*)(wv + (1 * 16 + m) * 64 + ch0));
        acc_v1 = __builtin_amdgcn_mfma_f32_16x16x16f16(wv1, bb, acc_v1, 0, 0, 0);
        half4 wv2 = cvtf4(*(const float4x*)(wv + (2 * 16 + m) * 64 + ch0));
        acc_v2 = __builtin_amdgcn_mfma_f32_16x16x16f16(wv2, bb, acc_v2, 0, 0, 0);
        half4 wv3 = cvtf4(*(const float4x*)(wv + (3 * 16 + m) * 64 + ch0));
        acc_v3 = __builtin_amdgcn_mfma_f32_16x16x16f16(wv3, bb, acc_v3, 0, 0, 0);
    }

    int px = pix0 + m;                       // output pixel (col = lane&15)
    if (g == 0) {
        half4 q0, q1, k0;
#pragma unroll
        for (int r = 0; r < 4; ++r) {
            q0[r] = (half_t)((acc_qa[r] + bq_ab[r]) * LOG2E);
            q1[r] = (half_t)((acc_qc[r] + bq_bc[r]) * LOG2E);
            k0[r] = (half_t)(acc_k[r] + bk_ab[r]);
        }
        *(half4*)(qp + ((bz * 2 + 0) * NPIX + px) * 4) = q0;
        *(half4*)(qp + ((bz * 2 + 1) * NPIX + px) * 4) = q1;
        *(half4*)(kp + ((bz * 2 + 0) * NPIX + px) * 4) = k0;
    } else if (g == 1) {
        half4 k1;
#pragma unroll
        for (int r = 0; r < 4; ++r) k1[r] = (half_t)(acc_k[r] + bk_bc[r]);
        *(half4*)(kp + ((bz * 2 + 1) * NPIX + px) * 4) = k1;
    }
#pragma unroll
    for (int r = 0; r < 4; ++r) {
        int c0 = 0 * 16 + 4 * g + r;
        vp[(bz * 64 + c0) * NPIX + px] = (half_t)(acc_v0[r] + bvb[c0]);
        int c1 = 1 * 16 + 4 * g + r;
        vp[(bz * 64 + c1) * NPIX + px] = (half_t)(acc_v1[r] + bvb[c1]);
        int c2 = 2 * 16 + 4 * g + r;
        vp[(bz * 64 + c2) * NPIX + px] = (half_t)(acc_v2[r] + bvb[c2]);
        int c3 = 3 * 16 + 4 * g + r;
        vp[(bz * 64 + c3) * NPIX + px] = (half_t)(acc_v3[r] + bvb[c3]);
    }
}

// ---------------- fused attention (flash, no-max softmax, split-K) ----------
// grid = 2000 (XCD-swizzled): (kh 10) x (bz 2) x (branch 2) x (qchunk 50).
// NO LDS, NO barriers: V (800KB/bz) and K are L2/L1-resident; each wave loads
// its own K/V fragments directly, one 16-key step ahead (register prefetch).
// Scores: mfma16x16x16f16(A=K,B=Q) -> lane holds S[m=4g+r][q] == PV B-frag layout.
__global__ __launch_bounds__(256) void attn_kernel(
    const half_t* __restrict__ qp, const half_t* __restrict__ kp,
    const half_t* __restrict__ vp, float* __restrict__ num, float* __restrict__ lsum)
{
    int bid = blockIdx.x;
    int swz = (bid & 7) * 250 + (bid >> 3);   // bijective (2000 = 8*250)
    int qc = swz % 50;
    int br = (swz / 50) & 1;
    int bz = (swz / 100) & 1;
    int kh = swz / 200;                        // 0..9

    int tid = threadIdx.x;
    int lane = tid & 63, w = tid >> 6;
    int g = lane >> 4, qi = lane & 15;
    int qbase = qc * 128 + w * 32;

    const half_t* Q = qp + ((bz * 2 + br) * NPIX + qbase) * 4;
    const half_t* K = kp + ((bz * 2 + br) * NPIX + kh * KEYS) * 4;
    const half_t* V = vp + bz * 64 * NPIX + kh * KEYS;

    half4 hz = {(half_t)0, (half_t)0, (half_t)0, (half_t)0};
    half4 qf[QF];
#pragma unroll
    for (int i = 0; i < QF; ++i)
        qf[i] = (lane < 16) ? *(const half4*)(Q + (i * 16 + lane) * 4) : hz;

    float4x accs[QF][4] = {{{0,0,0,0},{0,0,0,0},{0,0,0,0},{0,0,0,0}},
                           {{0,0,0,0},{0,0,0,0},{0,0,0,0},{0,0,0,0}}};
    float lrun[QF] = {0.f, 0.f};

    // prologue: fragments for step 0
    half4 kc = (lane < 16) ? *(const half4*)(K + lane * 4) : hz;
    half4 vc0 = *(const half4*)(V + (0 * 16 + qi) * NPIX + g * 4);
    half4 vc1 = *(const half4*)(V + (1 * 16 + qi) * NPIX + g * 4);
    half4 vc2 = *(const half4*)(V + (2 * 16 + qi) * NPIX + g * 4);
    half4 vc3 = *(const half4*)(V + (3 * 16 + qi) * NPIX + g * 4);

    for (int ts = 0; ts < NSTEP; ++ts) {
        bool more = (ts + 1 < NSTEP);
        half4 kn = hz, vn0, vn1, vn2, vn3;
        if (more) {     // issue next-step loads early; consumed after compute
            int mt = (ts + 1) * 16;
            kn = (lane < 16) ? *(const half4*)(K + (mt + lane) * 4) : hz;
            vn0 = *(const half4*)(V + (0 * 16 + qi) * NPIX + mt + g * 4);
            vn1 = *(const half4*)(V + (1 * 16 + qi) * NPIX + mt + g * 4);
            vn2 = *(const half4*)(V + (2 * 16 + qi) * NPIX + mt + g * 4);
            vn3 = *(const half4*)(V + (3 * 16 + qi) * NPIX + mt + g * 4);
        }
#pragma unroll
        for (int i = 0; i < QF; ++i) {
            float4x zero = {0.f, 0.f, 0.f, 0.f};
            float4x sc = __builtin_amdgcn_mfma_f32_16x16x16f16(kc, qf[i], zero, 0, 0, 0);
            // no-max softmax: |s*log2e| < ~3, exp2 always in range; raw v_exp_f32
            float p0 = fast_exp2(sc[0]), p1 = fast_exp2(sc[1]);
            float p2 = fast_exp2(sc[2]), p3 = fast_exp2(sc[3]);
            lrun[i] += (p0 + p1) + (p2 + p3);
            union { fp16x2 h2[2]; half4 h4; } pk;
            pk.h2[0] = __builtin_amdgcn_cvt_pkrtz(p0, p1);
            pk.h2[1] = __builtin_amdgcn_cvt_pkrtz(p2, p3);
            half4 pf = pk.h4;
            accs[i][0] = __builtin_amdgcn_mfma_f32_16x16x16f16(vc0, pf, accs[i][0], 0, 0, 0);
            accs[i][1] = __builtin_amdgcn_mfma_f32_16x16x16f16(vc1, pf, accs[i][1], 0, 0, 0);
            accs[i][2] = __builtin_amdgcn_mfma_f32_16x16x16f16(vc2, pf, accs[i][2], 0, 0, 0);
            accs[i][3] = __builtin_amdgcn_mfma_f32_16x16x16f16(vc3, pf, accs[i][3], 0, 0, 0);
        }
        kc = kn; vc0 = vn0; vc1 = vn1; vc2 = vn2; vc3 = vn3;
    }

    float* numb = num + (bz * 2 + br) * 64 * NPIX;
#pragma unroll
    for (int i = 0; i < QF; ++i) {
        float l = lrun[i];
        l += __shfl_xor(l, 16, 64);
        l += __shfl_xor(l, 32, 64);
        int q = qbase + i * 16 + qi;
        if (g == 0) atomicAdd(&lsum[(bz * 2 + br) * NPIX + q], l);
#pragma unroll
        for (int cb = 0; cb < 4; ++cb)
#pragma unroll
            for (int r = 0; r < 4; ++r)
                atomicAdd(&numb[(cb * 16 + 4 * g + r) * NPIX + q], accs[i][cb][r]);
    }
}

// one thread per (bz, c, n4), float4
__global__ __launch_bounds__(256) void norm_kernel(
    const float* __restrict__ num, const float* __restrict__ lsum, float* __restrict__ out)
{
    int tid = blockIdx.x * 256 + threadIdx.x;
    int n4 = tid % 1600;
    int c  = (tid / 1600) & 63;
    int bz = tid / (1600 * 64);
    float4x lA = *(const float4x*)(lsum + (bz * 2 + 0) * NPIX + n4 * 4);
    float4x lC = *(const float4x*)(lsum + (bz * 2 + 1) * NPIX + n4 * 4);
    float4x vA = *(const float4x*)(num + ((bz * 2 + 0) * 64 + c) * NPIX + n4 * 4);
    float4x vC = *(const float4x*)(num + ((bz * 2 + 1) * 64 + c) * NPIX + n4 * 4);
    float4x r;
#pragma unroll
    for (int j = 0; j < 4; ++j)
        r[j] = 0.5f * (vA[j] * __builtin_amdgcn_rcpf(lA[j]) +
                       vC[j] * __builtin_amdgcn_rcpf(lC[j]));
    *(float4x*)(out + (bz * 64 + c) * NPIX + n4 * 4) = r;
}

extern "C" void kernel_launch(void* const* d_in, const int* in_sizes, int n_in,
                              void* d_out, int out_size, void* d_ws, size_t ws_size,
                              hipStream_t stream) {
    (void)in_sizes; (void)n_in; (void)out_size; (void)ws_size;
    const float* a     = (const float*)d_in[0];
    const float* b     = (const float*)d_in[1];
    const float* c     = (const float*)d_in[2];
    const float* wq_ab = (const float*)d_in[3];
    const float* bq_ab = (const float*)d_in[4];
    const float* wk_ab = (const float*)d_in[5];
    const float* bk_ab = (const float*)d_in[6];
    const float* wq_bc = (const float*)d_in[7];
    const float* bq_bc = (const float*)d_in[8];
    const float* wk_bc = (const float*)d_in[9];
    const float* bk_bc = (const float*)d_in[10];
    const float* wv    = (const float*)d_in[11];
    const float* bv    = (const float*)d_in[12];
    float* out = (float*)d_out;

    // workspace: qp | kp | vp | num | lsum  (num+lsum zeroed by proj_kernel)
    half_t* qp = (half_t*)d_ws;
    half_t* kp = qp + 2 * 2 * NPIX * 4;
    half_t* vp = kp + 2 * 2 * NPIX * 4;
    float* num  = (float*)(vp + 2 * 64 * NPIX);
    float* lsum = num + 2 * 2 * 64 * NPIX;

    proj_kernel<<<264, 256, 0, stream>>>(a, b, c, wq_ab, bq_ab, wk_ab, bk_ab,
                                         wq_bc, bq_bc, wk_bc, bk_bc, wv, bv,
                                         qp, kp, vp, num);
    attn_kernel<<<2000, 256, 0, stream>>>(qp, kp, vp, num, lsum);
    norm_kernel<<<800, 256, 0, stream>>>(num, lsum, out);
}